// Round 3
// baseline (2086.762 us; speedup 1.0000x reference)
//
#include <hip/hip_runtime.h>

// DiscreteKeyValueBottleneck on MI355X (gfx950)
// B=4 T=1024 H=12 C=4096 DK=DV=64, N=B*T=4096, DIM=768
//
// The harness reference ("np") computes d2 = (x2 - 2*dots) + e2 in float32 at
// magnitude ~64; its rounding (ulp ~7.6e-6, per-candidate perturbation <=1.5e-5
// vs exact) flips the argmin for ~200 of 49152 queries. Rounds 1-2 proved our
// exact argmin != np argmin (identical absmax for fp32 and fp64 passes).
// Strategy: fast exact pass-1 with top-2 margin; queries with s-margin < TAU
// (d2-margin < 2*TAU) are re-resolved by bit-exact replication of numpy fp32:
//   x2/e2:  np.sum pairwise (8 accumulators over 64, ((r0+r1)+(r2+r3))+...)
//   dots:   np.einsum optimize=False contig_contig_outstride0_two, npyv SSE3
//           baseline: 4 lanes, no FMA, per-16 block chain p0+(p4+(p8+(p12+S))),
//           horizontal (S0+S1)+(S2+S3)
//   d2:     fl(fl(x2 - 2*dot) + e2), np.argmin = first occurrence
// TAU = 1e-4 gives >=6x safety over the perturbation bound even for x2>=128.

#define HEADS 12
#define CODES 4096
#define DKI   64
#define DVI   64
#define NTOK  4096
#define DIMX  768
#define QT    64
#define CCH   64
#define EPAD  68
#define TAU   1e-4f
#define WLCAP 32768

// ---------------- numpy bit-exact helpers (fp32, contraction OFF) -----------

// np.sum(a*a, axis=-1) over 64 contiguous floats: pairwise_sum n=64 path.
__device__ __forceinline__ float np_sumsq64(const float* __restrict__ a) {
#pragma clang fp contract(off)
    float r[8];
#pragma unroll
    for (int j = 0; j < 8; ++j) r[j] = a[j] * a[j];
#pragma unroll
    for (int i = 8; i < 64; i += 8)
#pragma unroll
        for (int j = 0; j < 8; ++j) r[j] += a[i + j] * a[i + j];
    return ((r[0] + r[1]) + (r[2] + r[3])) + ((r[4] + r[5]) + (r[6] + r[7]));
}

// np.einsum contraction over 64 floats: npyv SSE (4 lanes, mul+add separate),
// blocks of 16 with chain vaccum = p0 + (p1 + (p2 + (p3 + vaccum))) per lane,
// then hadd-style horizontal (S0+S1)+(S2+S3).
__device__ __forceinline__ float np_dot64(const float* __restrict__ xx,
                                          const float* __restrict__ ee) {
#pragma clang fp contract(off)
    float S0 = 0.f, S1 = 0.f, S2 = 0.f, S3 = 0.f;
#pragma unroll
    for (int t = 0; t < 64; t += 16) {
        float p[16];
#pragma unroll
        for (int j = 0; j < 16; ++j) p[j] = xx[t + j] * ee[t + j];
        S0 = p[0] + (p[4] + (p[8]  + (p[12] + S0)));
        S1 = p[1] + (p[5] + (p[9]  + (p[13] + S1)));
        S2 = p[2] + (p[6] + (p[10] + (p[14] + S2)));
        S3 = p[3] + (p[7] + (p[11] + (p[15] + S3)));
    }
    return (S0 + S1) + (S2 + S3);
}

// ---------------- kernels ---------------------------------------------------

// e2np[h,c] = np-bit-exact sum(ke[h,c,:]^2); also zero the worklist counter.
__global__ __launch_bounds__(256) void e2np_kernel(const float* __restrict__ ke,
                                                   float* __restrict__ e2np,
                                                   int* __restrict__ wl_count) {
    if (blockIdx.x == 0 && threadIdx.x == 0) *wl_count = 0;
    int idx = blockIdx.x * 256 + threadIdx.x;
    if (idx >= HEADS * CODES) return;
    float er[DKI];
    const float4* p = reinterpret_cast<const float4*>(ke + (size_t)idx * DKI);
#pragma unroll
    for (int i = 0; i < DKI / 4; ++i) {
        float4 v = p[i];
        er[i * 4 + 0] = v.x; er[i * 4 + 1] = v.y;
        er[i * 4 + 2] = v.z; er[i * 4 + 3] = v.w;
    }
    e2np[idx] = np_sumsq64(er);
}

// Pass 1: exact fp32 scan, top-2 margins, gather; flag ambiguous queries.
__global__ __launch_bounds__(256) void dkvb_kernel(const float* __restrict__ x,
                                                   const float* __restrict__ ke,
                                                   const float* __restrict__ values,
                                                   const float* __restrict__ e2np,
                                                   int* __restrict__ wl_count,
                                                   int* __restrict__ wl,
                                                   float* __restrict__ out) {
    __shared__ __align__(16) float Xs[QT][EPAD];
    __shared__ __align__(16) float Es[CCH][EPAD];
    __shared__ float e2s[CCH];
    __shared__ float bval[QT][16];
    __shared__ float bval2[QT][16];
    __shared__ int   bidx[QT][16];
    __shared__ int   fin[QT];

    const int tid = threadIdx.x;
    const int h  = blockIdx.y;
    const int q0 = blockIdx.x * QT;

#pragma unroll
    for (int k = 0; k < 4; ++k) {
        int f   = tid + k * 256;
        int row = f >> 4;
        int col = (f & 15) << 2;
        float4 v = *reinterpret_cast<const float4*>(
            x + (size_t)(q0 + row) * DIMX + h * DKI + col);
        Xs[row][col]     = v.x; Xs[row][col + 1] = v.y;
        Xs[row][col + 2] = v.z; Xs[row][col + 3] = v.w;
    }

    const int tq = tid >> 4;
    const int tc = tid & 15;

    float bv[4], bv2[4]; int bi[4];
#pragma unroll
    for (int i = 0; i < 4; ++i) { bv[i] = -1e30f; bv2[i] = -1e30f; bi[i] = 0; }

    for (int c0 = 0; c0 < CODES; c0 += CCH) {
        __syncthreads();
#pragma unroll
        for (int k = 0; k < 4; ++k) {
            int f   = tid + k * 256;
            int row = f >> 4;
            int col = (f & 15) << 2;
            float4 v = *reinterpret_cast<const float4*>(
                ke + (size_t)h * CODES * DKI + (size_t)(c0 + row) * DKI + col);
            Es[row][col]     = v.x; Es[row][col + 1] = v.y;
            Es[row][col + 2] = v.z; Es[row][col + 3] = v.w;
        }
        if (tid < CCH) e2s[tid] = 0.5f * e2np[h * CODES + c0 + tid];
        __syncthreads();

        float acc[4][4];
#pragma unroll
        for (int i = 0; i < 4; ++i)
#pragma unroll
            for (int j = 0; j < 4; ++j) acc[i][j] = 0.f;

#pragma unroll
        for (int d4 = 0; d4 < DKI / 4; ++d4) {
            float4 xv[4], ev[4];
#pragma unroll
            for (int i = 0; i < 4; ++i)
                xv[i] = *reinterpret_cast<const float4*>(&Xs[tq * 4 + i][d4 * 4]);
#pragma unroll
            for (int j = 0; j < 4; ++j)
                ev[j] = *reinterpret_cast<const float4*>(&Es[tc * 4 + j][d4 * 4]);
#pragma unroll
            for (int i = 0; i < 4; ++i)
#pragma unroll
                for (int j = 0; j < 4; ++j) {
                    acc[i][j] += xv[i].x * ev[j].x;
                    acc[i][j] += xv[i].y * ev[j].y;
                    acc[i][j] += xv[i].z * ev[j].z;
                    acc[i][j] += xv[i].w * ev[j].w;
                }
        }

#pragma unroll
        for (int i = 0; i < 4; ++i)
#pragma unroll
            for (int j = 0; j < 4; ++j) {
                float s = acc[i][j] - e2s[tc * 4 + j];
                int   c = c0 + tc * 4 + j;
                if (s > bv[i])       { bv2[i] = bv[i]; bv[i] = s; bi[i] = c; }
                else if (s > bv2[i]) { bv2[i] = s; }
            }
    }

#pragma unroll
    for (int i = 0; i < 4; ++i) {
        bval [tq * 4 + i][tc] = bv[i];
        bval2[tq * 4 + i][tc] = bv2[i];
        bidx [tq * 4 + i][tc] = bi[i];
    }
    __syncthreads();
    if (tid < QT) {
        float best = -1e30f, sec = -1e30f;
        int   bc = 0x7fffffff;
#pragma unroll
        for (int l = 0; l < 16; ++l) {
            float v1 = bval[tid][l], v2 = bval2[tid][l];
            int   c  = bidx[tid][l];
            if (v1 > best || (v1 == best && c < bc)) {
                sec = fmaxf(best, v2); best = v1; bc = c;
            } else {
                sec = fmaxf(sec, v1);
            }
        }
        fin[tid] = bc;
        if (best - sec < TAU) {
            int slot = atomicAdd(wl_count, 1);
            if (slot < WLCAP) wl[slot] = (h << 16) | (q0 + tid);
        }
    }
    __syncthreads();

#pragma unroll
    for (int k = 0; k < 4; ++k) {
        int f   = tid + k * 256;
        int row = f >> 4;
        int col = (f & 15) << 2;
        int idx = fin[row];
        float4 v = *reinterpret_cast<const float4*>(
            values + (size_t)h * CODES * DVI + (size_t)idx * DVI + col);
        *reinterpret_cast<float4*>(
            out + (size_t)(q0 + row) * DIMX + h * DVI + col) = v;
    }
}

// Pass 2: numpy-bit-exact re-argmin for flagged queries.
__global__ __launch_bounds__(64) void np_recheck(const float* __restrict__ x,
                                                 const float* __restrict__ ke,
                                                 const float* __restrict__ values,
                                                 const float* __restrict__ e2np,
                                                 const int* __restrict__ wl_count,
                                                 const int* __restrict__ wl,
                                                 float* __restrict__ out) {
    __shared__ float xs[DKI];
    __shared__ float rv[64];
    __shared__ int   ri[64];
    __shared__ int   bcast;

    const int t = threadIdx.x;
    int cnt = *wl_count;
    if (cnt > WLCAP) cnt = WLCAP;

    for (int e = blockIdx.x; e < cnt; e += gridDim.x) {
        __syncthreads();                       // protect xs reuse
        int ent = wl[e];
        int h = ent >> 16, n = ent & 0xffff;
        xs[t] = x[(size_t)n * DIMX + h * DKI + t];
        __syncthreads();

        // np-exact x2 (every lane computes the same value)
        float x2 = np_sumsq64(xs);

        float best = 3.4e38f; int bestc = 0x7fffffff;
        for (int k = 0; k < CODES / 64; ++k) {
            int c = k * 64 + t;
            float er[DKI];
            const float4* p = reinterpret_cast<const float4*>(
                ke + ((size_t)h * CODES + c) * DKI);
#pragma unroll
            for (int i = 0; i < DKI / 4; ++i) {
                float4 v = p[i];
                er[i * 4 + 0] = v.x; er[i * 4 + 1] = v.y;
                er[i * 4 + 2] = v.z; er[i * 4 + 3] = v.w;
            }
            float dot = np_dot64(xs, er);
            float d2;
            {
#pragma clang fp contract(off)
                d2 = (x2 - 2.0f * dot) + e2np[h * CODES + c];
            }
            if (d2 < best) { best = d2; bestc = c; }   // ascending c per lane
        }
        rv[t] = best; ri[t] = bestc;
        __syncthreads();
        if (t == 0) {
            float bb = rv[0]; int bc = ri[0];
#pragma unroll
            for (int l = 1; l < 64; ++l) {
                if (rv[l] < bb || (rv[l] == bb && ri[l] < bc)) {
                    bb = rv[l]; bc = ri[l];
                }
            }
            bcast = bc;
        }
        __syncthreads();
        int c = bcast;
        out[(size_t)n * DIMX + h * DVI + t] =
            values[((size_t)h * CODES + c) * DVI + t];
    }
}

extern "C" void kernel_launch(void* const* d_in, const int* in_sizes, int n_in,
                              void* d_out, int out_size, void* d_ws, size_t ws_size,
                              hipStream_t stream) {
    const float* x      = (const float*)d_in[0];
    // d_in[1] = mask (all ones; unused)
    const float* ke     = (const float*)d_in[2];
    const float* values = (const float*)d_in[3];
    // d_in[4] = key_optim (unused)
    float* out = (float*)d_out;

    float* e2np     = (float*)d_ws;                          // 49152 floats
    int*   wl_count = (int*)((char*)d_ws + HEADS * CODES * sizeof(float));
    int*   wl       = wl_count + 4;                          // WLCAP ints

    e2np_kernel<<<dim3((HEADS * CODES + 255) / 256), dim3(256), 0, stream>>>(
        ke, e2np, wl_count);
    dkvb_kernel<<<dim3(NTOK / QT, HEADS), dim3(256), 0, stream>>>(
        x, ke, values, e2np, wl_count, wl, out);
    np_recheck<<<dim3(512), dim3(64), 0, stream>>>(
        x, ke, values, e2np, wl_count, wl, out);
}

// Round 4
// 653.538 us; speedup vs baseline: 3.1930x; 3.1930x over previous
//
#include <hip/hip_runtime.h>

// DiscreteKeyValueBottleneck on MI355X (gfx950)
// B=4 T=1024 H=12 C=4096 DK=DV=64, N=B*T=4096, DIM=768
//
// Round 3 passed (absmax=0) with margin-filter + numpy-bit-exact recheck, but
// pass-1 (fp32 VALU, 4x4 register tile) spilled (VGPR=256, WRITE 310MB) ->
// 2 ms. Round 4: pass-1 scores via split-bf16 MFMA (xh*eh + xh*el + xl*eh,
// 3x mfma_f32_16x16x32_bf16, fp32 accum). Approx error <~2e-6 (dot units);
// np's own differential rounding <=1.6e-5; TAU=2e-4 margin flags ~2-4% of
// queries for the bit-exact np recheck (unchanged from round 3).

#define HEADS 12
#define CODES 4096
#define DKI   64
#define DVI   64
#define NTOK  4096
#define DIMX  768
#define QT    64
#define TAU   2e-4f
#define WLCAP 32768

typedef short bf16x8 __attribute__((ext_vector_type(8)));
typedef float f32x4  __attribute__((ext_vector_type(4)));

__device__ __forceinline__ unsigned short f2bf(float f) {   // RNE
    unsigned int u = __float_as_uint(f);
    return (unsigned short)((u + 0x7fff + ((u >> 16) & 1)) >> 16);
}
__device__ __forceinline__ float bf2f(unsigned short h) {
    return __uint_as_float(((unsigned int)h) << 16);
}

// ---------------- numpy bit-exact helpers (fp32, contraction OFF) -----------
__device__ __forceinline__ float np_sumsq64(const float* __restrict__ a) {
#pragma clang fp contract(off)
    float r[8];
#pragma unroll
    for (int j = 0; j < 8; ++j) r[j] = a[j] * a[j];
#pragma unroll
    for (int i = 8; i < 64; i += 8)
#pragma unroll
        for (int j = 0; j < 8; ++j) r[j] += a[i + j] * a[i + j];
    return ((r[0] + r[1]) + (r[2] + r[3])) + ((r[4] + r[5]) + (r[6] + r[7]));
}

__device__ __forceinline__ float np_dot64(const float* __restrict__ xx,
                                          const float* __restrict__ ee) {
#pragma clang fp contract(off)
    float S0 = 0.f, S1 = 0.f, S2 = 0.f, S3 = 0.f;
#pragma unroll
    for (int t = 0; t < 64; t += 16) {
        float p[16];
#pragma unroll
        for (int j = 0; j < 16; ++j) p[j] = xx[t + j] * ee[t + j];
        S0 = p[0] + (p[4] + (p[8]  + (p[12] + S0)));
        S1 = p[1] + (p[5] + (p[9]  + (p[13] + S1)));
        S2 = p[2] + (p[6] + (p[10] + (p[14] + S2)));
        S3 = p[3] + (p[7] + (p[11] + (p[15] + S3)));
    }
    return (S0 + S1) + (S2 + S3);
}

// ---- prep: per code row, np-exact e2 + bf16 hi/lo split of ke --------------
__global__ __launch_bounds__(256) void prep_ke(const float* __restrict__ ke,
                                               unsigned short* __restrict__ Eh,
                                               unsigned short* __restrict__ El,
                                               float* __restrict__ e2np,
                                               float* __restrict__ e2half,
                                               int* __restrict__ wl_count) {
    if (blockIdx.x == 0 && threadIdx.x == 0) *wl_count = 0;
    int idx = blockIdx.x * 256 + threadIdx.x;
    if (idx >= HEADS * CODES) return;
    float er[DKI];
    const float4* p = reinterpret_cast<const float4*>(ke + (size_t)idx * DKI);
#pragma unroll
    for (int i = 0; i < DKI / 4; ++i) {
        float4 v = p[i];
        er[i * 4 + 0] = v.x; er[i * 4 + 1] = v.y;
        er[i * 4 + 2] = v.z; er[i * 4 + 3] = v.w;
    }
    float e2 = np_sumsq64(er);
    e2np[idx]   = e2;
    e2half[idx] = 0.5f * e2;
    ushort4* hq = reinterpret_cast<ushort4*>(Eh + (size_t)idx * DKI);
    ushort4* lq = reinterpret_cast<ushort4*>(El + (size_t)idx * DKI);
#pragma unroll
    for (int i = 0; i < DKI / 4; ++i) {
        ushort4 hv, lv;
        unsigned short h0, h1, h2, h3;
        h0 = f2bf(er[i*4+0]); h1 = f2bf(er[i*4+1]);
        h2 = f2bf(er[i*4+2]); h3 = f2bf(er[i*4+3]);
        hv.x = h0; hv.y = h1; hv.z = h2; hv.w = h3;
        lv.x = f2bf(er[i*4+0] - bf2f(h0));
        lv.y = f2bf(er[i*4+1] - bf2f(h1));
        lv.z = f2bf(er[i*4+2] - bf2f(h2));
        lv.w = f2bf(er[i*4+3] - bf2f(h3));
        hq[i] = hv; lq[i] = lv;
    }
}

// ---- pass 1: split-bf16 MFMA scores, top-2 margin, gather ------------------
__global__ __launch_bounds__(256) void dkvb_mfma(const float* __restrict__ x,
                                                 const unsigned short* __restrict__ Eh,
                                                 const unsigned short* __restrict__ El,
                                                 const float* __restrict__ values,
                                                 const float* __restrict__ e2half,
                                                 int* __restrict__ wl_count,
                                                 int* __restrict__ wl,
                                                 float* __restrict__ out) {
    __shared__ int fin[QT];

    const int tid  = threadIdx.x;
    const int h    = blockIdx.y;
    const int q0   = blockIdx.x * QT;
    const int w    = tid >> 6;        // wave 0..3 -> queries q0+16w..+15
    const int lane = tid & 63;
    const int n    = lane & 15;       // A row m / B col n / D col n
    const int quad = lane >> 4;       // k-group; D rows quad*4+r

    // A fragments: A[m=lane&15][k=quad*8+j], k-chunks k0 in {0,32}, hi+lo.
    const float* xrow = x + (size_t)(q0 + 16 * w + n) * DIMX + h * DKI;
    bf16x8 ah[2], al[2];
#pragma unroll
    for (int k0 = 0; k0 < 2; ++k0) {
        const float* p = xrow + k0 * 32 + quad * 8;
        bf16x8 hi, lo;
#pragma unroll
        for (int j = 0; j < 8; ++j) {
            float f = p[j];
            unsigned short hb = f2bf(f);
            hi[j] = (short)hb;
            lo[j] = (short)f2bf(f - bf2f(hb));
        }
        ah[k0] = hi; al[k0] = lo;
    }

    // B fragment base: B[k][n] = E[c0+n][k0+quad*8+j]
    const bf16x8* ehp = reinterpret_cast<const bf16x8*>(
        Eh + ((size_t)h * CODES + n) * DKI + quad * 8);
    const bf16x8* elp = reinterpret_cast<const bf16x8*>(
        El + ((size_t)h * CODES + n) * DKI + quad * 8);
    const float* e2p = e2half + h * CODES + n;

    float bv[4], bv2[4]; int bi[4];
#pragma unroll
    for (int r = 0; r < 4; ++r) { bv[r] = -1e30f; bv2[r] = -1e30f; bi[r] = 0; }

    for (int c0 = 0; c0 < CODES; c0 += 32) {
        // two independent 16-code sub-chunks for ILP
        const int u0 = c0 * 8;            // bf16x8 units: 8 per code row
        const int u1 = u0 + 128;
        bf16x8 bh0 = ehp[u0], bh1 = ehp[u0 + 4];
        bf16x8 bl0 = elp[u0], bl1 = elp[u0 + 4];
        bf16x8 ch0 = ehp[u1], ch1 = ehp[u1 + 4];
        bf16x8 cl0 = elp[u1], cl1 = elp[u1 + 4];
        float e2a = e2p[c0], e2b = e2p[c0 + 16];
        f32x4 acc0 = {-e2a, -e2a, -e2a, -e2a};
        f32x4 acc1 = {-e2b, -e2b, -e2b, -e2b};

        acc0 = __builtin_amdgcn_mfma_f32_16x16x32_bf16(ah[0], bh0, acc0, 0, 0, 0);
        acc1 = __builtin_amdgcn_mfma_f32_16x16x32_bf16(ah[0], ch0, acc1, 0, 0, 0);
        acc0 = __builtin_amdgcn_mfma_f32_16x16x32_bf16(ah[1], bh1, acc0, 0, 0, 0);
        acc1 = __builtin_amdgcn_mfma_f32_16x16x32_bf16(ah[1], ch1, acc1, 0, 0, 0);
        acc0 = __builtin_amdgcn_mfma_f32_16x16x32_bf16(ah[0], bl0, acc0, 0, 0, 0);
        acc1 = __builtin_amdgcn_mfma_f32_16x16x32_bf16(ah[0], cl0, acc1, 0, 0, 0);
        acc0 = __builtin_amdgcn_mfma_f32_16x16x32_bf16(al[0], bh0, acc0, 0, 0, 0);
        acc1 = __builtin_amdgcn_mfma_f32_16x16x32_bf16(al[0], ch0, acc1, 0, 0, 0);
        acc0 = __builtin_amdgcn_mfma_f32_16x16x32_bf16(ah[1], bl1, acc0, 0, 0, 0);
        acc1 = __builtin_amdgcn_mfma_f32_16x16x32_bf16(ah[1], cl1, acc1, 0, 0, 0);
        acc0 = __builtin_amdgcn_mfma_f32_16x16x32_bf16(al[1], bh1, acc0, 0, 0, 0);
        acc1 = __builtin_amdgcn_mfma_f32_16x16x32_bf16(al[1], ch1, acc1, 0, 0, 0);

        // top-2 update; codes ascend (c0.. then c0+16..): strict > keeps first
#pragma unroll
        for (int r = 0; r < 4; ++r) {
            float s = acc0[r];
            int   c = c0 + n;
            if (s > bv[r]) { bv2[r] = bv[r]; bv[r] = s; bi[r] = c; }
            else           { bv2[r] = fmaxf(bv2[r], s); }
        }
#pragma unroll
        for (int r = 0; r < 4; ++r) {
            float s = acc1[r];
            int   c = c0 + 16 + n;
            if (s > bv[r]) { bv2[r] = bv[r]; bv[r] = s; bi[r] = c; }
            else           { bv2[r] = fmaxf(bv2[r], s); }
        }
    }

    // cross-lane top-2 butterfly over the 16 lanes sharing quad (masks 1,2,4,8)
#pragma unroll
    for (int r = 0; r < 4; ++r) {
#pragma unroll
        for (int m = 1; m <= 8; m <<= 1) {
            float pv1 = __shfl_xor(bv[r],  m, 64);
            float pv2 = __shfl_xor(bv2[r], m, 64);
            int   pi  = __shfl_xor(bi[r],  m, 64);
            bool take = (pv1 > bv[r]) || (pv1 == bv[r] && pi < bi[r]);
            float lo1 = take ? bv[r] : pv1;          // loser of top comparison
            bv2[r] = fmaxf(lo1, fmaxf(bv2[r], pv2));
            bv[r]  = take ? pv1 : bv[r];
            bi[r]  = take ? pi  : bi[r];
        }
    }
    if (n == 0) {
#pragma unroll
        for (int r = 0; r < 4; ++r) {
            int ql = 16 * w + quad * 4 + r;
            fin[ql] = bi[r];
            if (bv[r] - bv2[r] < TAU) {
                int slot = atomicAdd(wl_count, 1);
                if (slot < WLCAP) wl[slot] = (h << 16) | (q0 + ql);
            }
        }
    }
    __syncthreads();

    // gather values[h, fin[q], :] -> out
#pragma unroll
    for (int k = 0; k < 4; ++k) {
        int f   = tid + k * 256;
        int row = f >> 4;
        int col = (f & 15) << 2;
        int idx = fin[row];
        float4 v = *reinterpret_cast<const float4*>(
            values + (size_t)h * CODES * DVI + (size_t)idx * DVI + col);
        *reinterpret_cast<float4*>(
            out + (size_t)(q0 + row) * DIMX + h * DVI + col) = v;
    }
}

// ---- pass 2: numpy-bit-exact re-argmin for flagged queries -----------------
__global__ __launch_bounds__(64) void np_recheck(const float* __restrict__ x,
                                                 const float* __restrict__ ke,
                                                 const float* __restrict__ values,
                                                 const float* __restrict__ e2np,
                                                 const int* __restrict__ wl_count,
                                                 const int* __restrict__ wl,
                                                 float* __restrict__ out) {
    __shared__ float xs[DKI];
    __shared__ float rv[64];
    __shared__ int   ri[64];
    __shared__ int   bcast;

    const int t = threadIdx.x;
    int cnt = *wl_count;
    if (cnt > WLCAP) cnt = WLCAP;

    for (int e = blockIdx.x; e < cnt; e += gridDim.x) {
        __syncthreads();
        int ent = wl[e];
        int h = ent >> 16, nq = ent & 0xffff;
        xs[t] = x[(size_t)nq * DIMX + h * DKI + t];
        __syncthreads();

        float x2 = np_sumsq64(xs);

        float best = 3.4e38f; int bestc = 0x7fffffff;
        for (int k = 0; k < CODES / 64; ++k) {
            int c = k * 64 + t;
            float er[DKI];
            const float4* p = reinterpret_cast<const float4*>(
                ke + ((size_t)h * CODES + c) * DKI);
#pragma unroll
            for (int i = 0; i < DKI / 4; ++i) {
                float4 v = p[i];
                er[i * 4 + 0] = v.x; er[i * 4 + 1] = v.y;
                er[i * 4 + 2] = v.z; er[i * 4 + 3] = v.w;
            }
            float dot = np_dot64(xs, er);
            float d2;
            {
#pragma clang fp contract(off)
                d2 = (x2 - 2.0f * dot) + e2np[h * CODES + c];
            }
            if (d2 < best) { best = d2; bestc = c; }
        }
        rv[t] = best; ri[t] = bestc;
        __syncthreads();
        if (t == 0) {
            float bb = rv[0]; int bc = ri[0];
#pragma unroll
            for (int l = 1; l < 64; ++l) {
                if (rv[l] < bb || (rv[l] == bb && ri[l] < bc)) {
                    bb = rv[l]; bc = ri[l];
                }
            }
            bcast = bc;
        }
        __syncthreads();
        int c = bcast;
        out[(size_t)nq * DIMX + h * DVI + t] =
            values[((size_t)h * CODES + c) * DVI + t];
    }
}

extern "C" void kernel_launch(void* const* d_in, const int* in_sizes, int n_in,
                              void* d_out, int out_size, void* d_ws, size_t ws_size,
                              hipStream_t stream) {
    const float* x      = (const float*)d_in[0];
    // d_in[1] = mask (all ones; unused)
    const float* ke     = (const float*)d_in[2];
    const float* values = (const float*)d_in[3];
    // d_in[4] = key_optim (unused)
    float* out = (float*)d_out;

    char* ws = (char*)d_ws;
    float* e2np     = (float*)ws;                         ws += HEADS * CODES * sizeof(float);
    float* e2half   = (float*)ws;                         ws += HEADS * CODES * sizeof(float);
    int*   wl_count = (int*)ws;                           ws += 16;
    int*   wl       = (int*)ws;                           ws += WLCAP * sizeof(int);
    unsigned short* Eh = (unsigned short*)ws;             ws += (size_t)HEADS * CODES * DKI * sizeof(unsigned short);
    unsigned short* El = (unsigned short*)ws;

    prep_ke<<<dim3((HEADS * CODES + 255) / 256), dim3(256), 0, stream>>>(
        ke, Eh, El, e2np, e2half, wl_count);
    dkvb_mfma<<<dim3(NTOK / QT, HEADS), dim3(256), 0, stream>>>(
        x, Eh, El, values, e2half, wl_count, wl, out);
    np_recheck<<<dim3(2048), dim3(64), 0, stream>>>(
        x, ke, values, e2np, wl_count, wl, out);
}

// Round 5
// 506.211 us; speedup vs baseline: 4.1223x; 1.2910x over previous
//
#include <hip/hip_runtime.h>

// DiscreteKeyValueBottleneck on MI355X (gfx950)
// B=4 T=1024 H=12 C=4096 DK=DV=64, N=B*T=4096, DIM=768
//
// Architecture (round 3/4, absmax=0): split-bf16 MFMA scores (xh*eh + xh*el
// + xl*eh), top-2 margin filter, numpy-bit-exact fp32 recheck of flagged
// queries. Round 5: attack latency-boundedness of pass-1 (was 378us at
// MfmaUtil 8.3%, 12 waves/CU): 2 query-tiles x 2 code-halves per 256-thread
// block -> 1536 blocks = 24 waves/CU; med3-based top-2 (4 instr/score);
// cross-half LDS merge; TAU 5e-5 (error budget: np differential <=1.5e-5,
// our score error ~1e-6). MFMA floor ~37us, VALU overlaps under it.

#define HEADS 12
#define CODES 4096
#define DKI   64
#define DVI   64
#define NTOK  4096
#define DIMX  768
#define TAU   5e-5f
#define WLCAP 32768

typedef short bf16x8 __attribute__((ext_vector_type(8)));
typedef float f32x4  __attribute__((ext_vector_type(4)));

__device__ __forceinline__ unsigned short f2bf(float f) {   // RNE
    unsigned int u = __float_as_uint(f);
    return (unsigned short)((u + 0x7fff + ((u >> 16) & 1)) >> 16);
}
__device__ __forceinline__ float bf2f(unsigned short h) {
    return __uint_as_float(((unsigned int)h) << 16);
}

// ---------------- numpy bit-exact helpers (fp32, contraction OFF) -----------
__device__ __forceinline__ float np_sumsq64(const float* __restrict__ a) {
#pragma clang fp contract(off)
    float r[8];
#pragma unroll
    for (int j = 0; j < 8; ++j) r[j] = a[j] * a[j];
#pragma unroll
    for (int i = 8; i < 64; i += 8)
#pragma unroll
        for (int j = 0; j < 8; ++j) r[j] += a[i + j] * a[i + j];
    return ((r[0] + r[1]) + (r[2] + r[3])) + ((r[4] + r[5]) + (r[6] + r[7]));
}

__device__ __forceinline__ float np_dot64(const float* __restrict__ xx,
                                          const float* __restrict__ ee) {
#pragma clang fp contract(off)
    float S0 = 0.f, S1 = 0.f, S2 = 0.f, S3 = 0.f;
#pragma unroll
    for (int t = 0; t < 64; t += 16) {
        float p[16];
#pragma unroll
        for (int j = 0; j < 16; ++j) p[j] = xx[t + j] * ee[t + j];
        S0 = p[0] + (p[4] + (p[8]  + (p[12] + S0)));
        S1 = p[1] + (p[5] + (p[9]  + (p[13] + S1)));
        S2 = p[2] + (p[6] + (p[10] + (p[14] + S2)));
        S3 = p[3] + (p[7] + (p[11] + (p[15] + S3)));
    }
    return (S0 + S1) + (S2 + S3);
}

// ---- prep: per code row, np-exact e2, -0.5*e2, bf16 hi/lo split ------------
__global__ __launch_bounds__(256) void prep_ke(const float* __restrict__ ke,
                                               unsigned short* __restrict__ Eh,
                                               unsigned short* __restrict__ El,
                                               float* __restrict__ e2np,
                                               float* __restrict__ m2half,
                                               int* __restrict__ wl_count) {
    if (blockIdx.x == 0 && threadIdx.x == 0) *wl_count = 0;
    int idx = blockIdx.x * 256 + threadIdx.x;
    if (idx >= HEADS * CODES) return;
    float er[DKI];
    const float4* p = reinterpret_cast<const float4*>(ke + (size_t)idx * DKI);
#pragma unroll
    for (int i = 0; i < DKI / 4; ++i) {
        float4 v = p[i];
        er[i * 4 + 0] = v.x; er[i * 4 + 1] = v.y;
        er[i * 4 + 2] = v.z; er[i * 4 + 3] = v.w;
    }
    float e2 = np_sumsq64(er);
    e2np[idx]   = e2;
    m2half[idx] = -0.5f * e2;
    ushort4* hq = reinterpret_cast<ushort4*>(Eh + (size_t)idx * DKI);
    ushort4* lq = reinterpret_cast<ushort4*>(El + (size_t)idx * DKI);
#pragma unroll
    for (int i = 0; i < DKI / 4; ++i) {
        ushort4 hv, lv;
        unsigned short h0 = f2bf(er[i*4+0]), h1 = f2bf(er[i*4+1]);
        unsigned short h2 = f2bf(er[i*4+2]), h3 = f2bf(er[i*4+3]);
        hv.x = h0; hv.y = h1; hv.z = h2; hv.w = h3;
        lv.x = f2bf(er[i*4+0] - bf2f(h0));
        lv.y = f2bf(er[i*4+1] - bf2f(h1));
        lv.z = f2bf(er[i*4+2] - bf2f(h2));
        lv.w = f2bf(er[i*4+3] - bf2f(h3));
        hq[i] = hv; lq[i] = lv;
    }
}

// ---- pass 1: split-bf16 MFMA scores; 2 qtiles x 2 code-halves per block ----
__global__ __launch_bounds__(256, 6) void dkvb_mfma(const float* __restrict__ x,
                                                    const unsigned short* __restrict__ Eh,
                                                    const unsigned short* __restrict__ El,
                                                    const float* __restrict__ values,
                                                    const float* __restrict__ m2half,
                                                    int* __restrict__ wl_count,
                                                    int* __restrict__ wl,
                                                    float* __restrict__ out) {
    __shared__ float sbv[4][16];
    __shared__ float sbv2[4][16];
    __shared__ int   sbi[4][16];
    __shared__ int   fin[32];

    const int tid  = threadIdx.x;
    const int h    = blockIdx.y;
    const int q0   = blockIdx.x * 32;
    const int w    = tid >> 6;        // wave 0..3
    const int lane = tid & 63;
    const int n    = lane & 15;       // A row m / B col n
    const int quad = lane >> 4;       // k-group; D rows quad*4+r
    const int qt   = w & 1;           // query tile within block
    const int half = w >> 1;          // code half: [0,2048) or [2048,4096)
    const int cbase = half * 2048;

    // A fragments for query q0 + qt*16 + n: A[m][k=quad*8+j], k0 in {0,32}
    const float* xrow = x + (size_t)(q0 + qt * 16 + n) * DIMX + h * DKI;
    bf16x8 ah[2], al[2];
#pragma unroll
    for (int k0 = 0; k0 < 2; ++k0) {
        const float* p = xrow + k0 * 32 + quad * 8;
        bf16x8 hi, lo;
#pragma unroll
        for (int j = 0; j < 8; ++j) {
            float f = p[j];
            unsigned short hb = f2bf(f);
            hi[j] = (short)hb;
            lo[j] = (short)f2bf(f - bf2f(hb));
        }
        ah[k0] = hi; al[k0] = lo;
    }

    const bf16x8* ehp = reinterpret_cast<const bf16x8*>(
        Eh + ((size_t)h * CODES + cbase + n) * DKI + quad * 8);
    const bf16x8* elp = reinterpret_cast<const bf16x8*>(
        El + ((size_t)h * CODES + cbase + n) * DKI + quad * 8);
    const float* m2p = m2half + h * CODES + cbase + n;

    float bv[4], bv2[4]; int bi[4];
#pragma unroll
    for (int r = 0; r < 4; ++r) { bv[r] = -1e30f; bv2[r] = -1e30f; bi[r] = 0; }

#pragma unroll 1
    for (int c0 = 0; c0 < 2048; c0 += 32) {
        const int u0 = c0 * 8;            // bf16x8 units (8 per code row)
        const int u1 = u0 + 128;
        bf16x8 bh0 = ehp[u0], bh1 = ehp[u0 + 4];
        bf16x8 bl0 = elp[u0], bl1 = elp[u0 + 4];
        bf16x8 ch0 = ehp[u1], ch1 = ehp[u1 + 4];
        bf16x8 cl0 = elp[u1], cl1 = elp[u1 + 4];
        float m2a = m2p[c0], m2b = m2p[c0 + 16];
        f32x4 acc0 = {m2a, m2a, m2a, m2a};
        f32x4 acc1 = {m2b, m2b, m2b, m2b};

        acc0 = __builtin_amdgcn_mfma_f32_16x16x32_bf16(ah[0], bh0, acc0, 0, 0, 0);
        acc1 = __builtin_amdgcn_mfma_f32_16x16x32_bf16(ah[0], ch0, acc1, 0, 0, 0);
        acc0 = __builtin_amdgcn_mfma_f32_16x16x32_bf16(ah[1], bh1, acc0, 0, 0, 0);
        acc1 = __builtin_amdgcn_mfma_f32_16x16x32_bf16(ah[1], ch1, acc1, 0, 0, 0);
        acc0 = __builtin_amdgcn_mfma_f32_16x16x32_bf16(ah[0], bl0, acc0, 0, 0, 0);
        acc1 = __builtin_amdgcn_mfma_f32_16x16x32_bf16(ah[0], cl0, acc1, 0, 0, 0);
        acc0 = __builtin_amdgcn_mfma_f32_16x16x32_bf16(al[0], bh0, acc0, 0, 0, 0);
        acc1 = __builtin_amdgcn_mfma_f32_16x16x32_bf16(al[0], ch0, acc1, 0, 0, 0);
        acc0 = __builtin_amdgcn_mfma_f32_16x16x32_bf16(ah[1], bl1, acc0, 0, 0, 0);
        acc1 = __builtin_amdgcn_mfma_f32_16x16x32_bf16(ah[1], cl1, acc1, 0, 0, 0);
        acc0 = __builtin_amdgcn_mfma_f32_16x16x32_bf16(al[1], bh1, acc0, 0, 0, 0);
        acc1 = __builtin_amdgcn_mfma_f32_16x16x32_bf16(al[1], ch1, acc1, 0, 0, 0);

        // top-2 update, 4 instr/score: med3 (2nd-best), max, cmp, cndmask
#pragma unroll
        for (int r = 0; r < 4; ++r) {
            float s = acc0[r];
            bv2[r] = __builtin_amdgcn_fmed3f(bv2[r], s, bv[r]);
            bool gt = s > bv[r];
            bi[r] = gt ? (cbase + c0 + n) : bi[r];
            bv[r] = fmaxf(bv[r], s);
        }
#pragma unroll
        for (int r = 0; r < 4; ++r) {
            float s = acc1[r];
            bv2[r] = __builtin_amdgcn_fmed3f(bv2[r], s, bv[r]);
            bool gt = s > bv[r];
            bi[r] = gt ? (cbase + c0 + 16 + n) : bi[r];
            bv[r] = fmaxf(bv[r], s);
        }
    }

    // cross-lane top-2 butterfly over the 16 n-lanes (masks 1,2,4,8)
#pragma unroll
    for (int r = 0; r < 4; ++r) {
#pragma unroll
        for (int m = 1; m <= 8; m <<= 1) {
            float pv1 = __shfl_xor(bv[r],  m, 64);
            float pv2 = __shfl_xor(bv2[r], m, 64);
            int   pi  = __shfl_xor(bi[r],  m, 64);
            bool take = (pv1 > bv[r]) || (pv1 == bv[r] && pi < bi[r]);
            float lo1 = take ? bv[r] : pv1;
            bv2[r] = fmaxf(lo1, fmaxf(bv2[r], pv2));
            bv[r]  = take ? pv1 : bv[r];
            bi[r]  = take ? pi  : bi[r];
        }
    }
    if (n == 0) {
#pragma unroll
        for (int r = 0; r < 4; ++r) {
            sbv [w][quad * 4 + r] = bv[r];
            sbv2[w][quad * 4 + r] = bv2[r];
            sbi [w][quad * 4 + r] = bi[r];
        }
    }
    __syncthreads();

    // merge the two code halves (waves t and t+2 share query tile t)
    if (tid < 32) {
        int q = tid, t = q >> 4, l = q & 15;
        float bvA = sbv[t][l],  bvB = sbv[t + 2][l];
        float b2A = sbv2[t][l], b2B = sbv2[t + 2][l];
        bool  tb  = bvB > bvA;                    // tie -> A (smaller index)
        float bvm  = tb ? bvB : bvA;
        int   bim  = tb ? sbi[t + 2][l] : sbi[t][l];
        float bv2m = fmaxf(fmaxf(b2A, b2B), fminf(bvA, bvB));
        fin[q] = bim;
        if (bvm - bv2m < TAU) {
            int slot = atomicAdd(wl_count, 1);
            if (slot < WLCAP) wl[slot] = (h << 16) | (q0 + q);
        }
    }
    __syncthreads();

    // gather values[h, fin[q], :] -> out, 32 rows x 16 float4
#pragma unroll
    for (int k = 0; k < 2; ++k) {
        int f   = tid + k * 256;
        int row = f >> 4;
        int col = (f & 15) << 2;
        int idx = fin[row];
        float4 v = *reinterpret_cast<const float4*>(
            values + (size_t)h * CODES * DVI + (size_t)idx * DVI + col);
        *reinterpret_cast<float4*>(
            out + (size_t)(q0 + row) * DIMX + h * DVI + col) = v;
    }
}

// ---- pass 2: numpy-bit-exact re-argmin for flagged queries -----------------
__global__ __launch_bounds__(64) void np_recheck(const float* __restrict__ x,
                                                 const float* __restrict__ ke,
                                                 const float* __restrict__ values,
                                                 const float* __restrict__ e2np,
                                                 const int* __restrict__ wl_count,
                                                 const int* __restrict__ wl,
                                                 float* __restrict__ out) {
    __shared__ float xs[DKI];
    __shared__ float rv[64];
    __shared__ int   ri[64];
    __shared__ int   bcast;

    const int t = threadIdx.x;
    int cnt = *wl_count;
    if (cnt > WLCAP) cnt = WLCAP;

    for (int e = blockIdx.x; e < cnt; e += gridDim.x) {
        __syncthreads();
        int ent = wl[e];
        int h = ent >> 16, nq = ent & 0xffff;
        xs[t] = x[(size_t)nq * DIMX + h * DKI + t];
        __syncthreads();

        float x2 = np_sumsq64(xs);

        float best = 3.4e38f; int bestc = 0x7fffffff;
        for (int k = 0; k < CODES / 64; ++k) {
            int c = k * 64 + t;
            float er[DKI];
            const float4* p = reinterpret_cast<const float4*>(
                ke + ((size_t)h * CODES + c) * DKI);
#pragma unroll
            for (int i = 0; i < DKI / 4; ++i) {
                float4 v = p[i];
                er[i * 4 + 0] = v.x; er[i * 4 + 1] = v.y;
                er[i * 4 + 2] = v.z; er[i * 4 + 3] = v.w;
            }
            float dot = np_dot64(xs, er);
            float d2;
            {
#pragma clang fp contract(off)
                d2 = (x2 - 2.0f * dot) + e2np[h * CODES + c];
            }
            if (d2 < best) { best = d2; bestc = c; }
        }
        rv[t] = best; ri[t] = bestc;
        __syncthreads();
        if (t == 0) {
            float bb = rv[0]; int bc = ri[0];
#pragma unroll
            for (int l = 1; l < 64; ++l) {
                if (rv[l] < bb || (rv[l] == bb && ri[l] < bc)) {
                    bb = rv[l]; bc = ri[l];
                }
            }
            bcast = bc;
        }
        __syncthreads();
        int c = bcast;
        out[(size_t)nq * DIMX + h * DVI + t] =
            values[((size_t)h * CODES + c) * DVI + t];
    }
}

extern "C" void kernel_launch(void* const* d_in, const int* in_sizes, int n_in,
                              void* d_out, int out_size, void* d_ws, size_t ws_size,
                              hipStream_t stream) {
    const float* x      = (const float*)d_in[0];
    // d_in[1] = mask (all ones; unused)
    const float* ke     = (const float*)d_in[2];
    const float* values = (const float*)d_in[3];
    // d_in[4] = key_optim (unused)
    float* out = (float*)d_out;

    char* ws = (char*)d_ws;
    float* e2np     = (float*)ws;             ws += HEADS * CODES * sizeof(float);
    float* m2half   = (float*)ws;             ws += HEADS * CODES * sizeof(float);
    int*   wl_count = (int*)ws;               ws += 16;
    int*   wl       = (int*)ws;               ws += WLCAP * sizeof(int);
    unsigned short* Eh = (unsigned short*)ws; ws += (size_t)HEADS * CODES * DKI * sizeof(unsigned short);
    unsigned short* El = (unsigned short*)ws;

    prep_ke<<<dim3((HEADS * CODES + 255) / 256), dim3(256), 0, stream>>>(
        ke, Eh, El, e2np, m2half, wl_count);
    dkvb_mfma<<<dim3(NTOK / 32, HEADS), dim3(256), 0, stream>>>(
        x, Eh, El, values, m2half, wl_count, wl, out);
    np_recheck<<<dim3(4096), dim3(64), 0, stream>>>(
        x, ke, values, e2np, wl_count, wl, out);
}

// Round 6
// 248.901 us; speedup vs baseline: 8.3839x; 2.0338x over previous
//
#include <hip/hip_runtime.h>

// DiscreteKeyValueBottleneck on MI355X (gfx950)
// B=4 T=1024 H=12 C=4096 DK=DV=64, N=B*T=4096, DIM=768
//
// Pipeline (absmax=0 since round 3): split-bf16 MFMA scores (xh*eh + xh*el +
// xl*eh), top-2 margin filter (TAU), numpy-bit-exact fp32 recheck of flagged
// queries. Round 6: pass-1 was L3-BW-bound (3.2 GB E-reads at 8.5 TB/s,
// occupancy-insensitive). Now: 32x32x16 MFMA (2x queries per B-read, 15%
// better rate), LDS-staged E via global_load_lds width=16 (double-buffered,
// shared by 2 query-waves -> 806 MB global), piece-major staged layout
// (conflict-free ds_read_b128), XCD-pinned heads (h = b%12 -> 3 heads/XCD
// ~3.2MB hot, L2-resident).

#define HEADS 12
#define CODES 4096
#define DKI   64
#define DVI   64
#define NTOK  4096
#define DIMX  768
#define TAU   5e-5f
#define WLCAP 32768

typedef short bf16x8 __attribute__((ext_vector_type(8)));
typedef float f32x16 __attribute__((ext_vector_type(16)));

__device__ __forceinline__ unsigned short f2bf(float f) {   // RNE
    unsigned int u = __float_as_uint(f);
    return (unsigned short)((u + 0x7fff + ((u >> 16) & 1)) >> 16);
}
__device__ __forceinline__ float bf2f(unsigned short h) {
    return __uint_as_float(((unsigned int)h) << 16);
}

__device__ __forceinline__ void async_load16(const void* g, void* l) {
    __builtin_amdgcn_global_load_lds(
        (const __attribute__((address_space(1))) unsigned int*)g,
        (__attribute__((address_space(3))) unsigned int*)l, 16, 0, 0);
}

// ---------------- numpy bit-exact helpers (fp32, contraction OFF) -----------
__device__ __forceinline__ float np_sumsq64(const float* __restrict__ a) {
#pragma clang fp contract(off)
    float r[8];
#pragma unroll
    for (int j = 0; j < 8; ++j) r[j] = a[j] * a[j];
#pragma unroll
    for (int i = 8; i < 64; i += 8)
#pragma unroll
        for (int j = 0; j < 8; ++j) r[j] += a[i + j] * a[i + j];
    return ((r[0] + r[1]) + (r[2] + r[3])) + ((r[4] + r[5]) + (r[6] + r[7]));
}

__device__ __forceinline__ float np_dot64(const float* __restrict__ xx,
                                          const float* __restrict__ ee) {
#pragma clang fp contract(off)
    float S0 = 0.f, S1 = 0.f, S2 = 0.f, S3 = 0.f;
#pragma unroll
    for (int t = 0; t < 64; t += 16) {
        float p[16];
#pragma unroll
        for (int j = 0; j < 16; ++j) p[j] = xx[t + j] * ee[t + j];
        S0 = p[0] + (p[4] + (p[8]  + (p[12] + S0)));
        S1 = p[1] + (p[5] + (p[9]  + (p[13] + S1)));
        S2 = p[2] + (p[6] + (p[10] + (p[14] + S2)));
        S3 = p[3] + (p[7] + (p[11] + (p[15] + S3)));
    }
    return (S0 + S1) + (S2 + S3);
}

// ---- prep: np-exact e2; Eh/El in transposed chunk-piece-code layout --------
// EhT layout (uint4=16B units): [(h*128 + chunk)*8 + piece]*32 + (c&31)
// i.e. per 32-code chunk: 8 pieces x 32 codes x 16B = 4KB contiguous.
__global__ __launch_bounds__(256) void prep_ke(const float* __restrict__ ke,
                                               uint4* __restrict__ EhT,
                                               uint4* __restrict__ ElT,
                                               float* __restrict__ e2np,
                                               float* __restrict__ m2half,
                                               int* __restrict__ wl_count) {
    if (blockIdx.x == 0 && threadIdx.x == 0) *wl_count = 0;
    int idx = blockIdx.x * 256 + threadIdx.x;
    if (idx >= HEADS * CODES) return;
    float er[DKI];
    const float4* p4 = reinterpret_cast<const float4*>(ke + (size_t)idx * DKI);
#pragma unroll
    for (int i = 0; i < DKI / 4; ++i) {
        float4 v = p4[i];
        er[i * 4 + 0] = v.x; er[i * 4 + 1] = v.y;
        er[i * 4 + 2] = v.z; er[i * 4 + 3] = v.w;
    }
    float e2 = np_sumsq64(er);
    e2np[idx]   = e2;
    m2half[idx] = -0.5f * e2;

    int h = idx >> 12, c = idx & 4095, ch = c >> 5, cc = c & 31;
    size_t base = ((size_t)(h * 128 + ch) * 8) * 32 + cc;
#pragma unroll
    for (int p = 0; p < 8; ++p) {
        unsigned int hb[8], lb[8];
#pragma unroll
        for (int j = 0; j < 8; ++j) {
            float f = er[p * 8 + j];
            unsigned short hh = f2bf(f);
            hb[j] = hh;
            lb[j] = f2bf(f - bf2f(hh));
        }
        uint4 hv, lv;
        hv.x = hb[0] | (hb[1] << 16); hv.y = hb[2] | (hb[3] << 16);
        hv.z = hb[4] | (hb[5] << 16); hv.w = hb[6] | (hb[7] << 16);
        lv.x = lb[0] | (lb[1] << 16); lv.y = lb[2] | (lb[3] << 16);
        lv.z = lb[4] | (lb[5] << 16); lv.w = lb[6] | (lb[7] << 16);
        EhT[base + p * 32] = hv;
        ElT[base + p * 32] = lv;
    }
}

// ---- pass 1: 32x32x16 split-bf16 MFMA, LDS-staged E, 64 queries/block ------
// 4 waves: wave w -> query tile qt=w&1 (32 q), code half=w>>1 (2048 codes).
// Wave w also stages matrix (w&1) of half (w>>1) via global_load_lds.
__global__ __launch_bounds__(256, 3) void dkvb_mfma(const float* __restrict__ x,
                                                    const char* __restrict__ EhT,
                                                    const char* __restrict__ ElT,
                                                    const float* __restrict__ values,
                                                    const float* __restrict__ m2half,
                                                    int* __restrict__ wl_count,
                                                    int* __restrict__ wl,
                                                    float* __restrict__ out) {
    __shared__ __align__(16) char ldsbuf[2][2][2][4096];   // [dbuf][half][mat]
    __shared__ float sbv[2][64], sbv2[2][64];
    __shared__ int   sbi[2][64];
    __shared__ int   fin[64];

    const int tid  = threadIdx.x;
    const int b    = blockIdx.x;
    const int h    = b % 12;            // XCD-pinned: b%8 cycles -> 3 heads/XCD
    const int q0   = (b / 12) * 64;
    const int w    = tid >> 6;
    const int lane = tid & 63;
    const int col  = lane & 31;         // B col n / D col (code)
    const int kh   = lane >> 5;         // k-half within K=16 step
    const int qt   = w & 1;
    const int half = w >> 1;
    const int cbase = half * 2048;

    // ---- A fragments: query m = q0+qt*32+col; step t: k = t*16 + kh*8 + j
    const float* xrow = x + (size_t)(q0 + qt * 32 + col) * DIMX + h * DKI;
    bf16x8 ah[4], al[4];
#pragma unroll
    for (int t = 0; t < 4; ++t) {
        const float* p = xrow + t * 16 + kh * 8;
        bf16x8 hi, lo;
#pragma unroll
        for (int j = 0; j < 8; ++j) {
            float f = p[j];
            unsigned short hb = f2bf(f);
            hi[j] = (short)hb;
            lo[j] = (short)f2bf(f - bf2f(hb));
        }
        ah[t] = hi; al[t] = lo;
    }

    // ---- staging pointers: wave w stages matrix (w&1) of half (w>>1)
    const char* gsrc = ((w & 1) ? ElT : EhT)
                     + ((size_t)(h * 128 + (w >> 1) * 64)) * 4096 + lane * 16;
    char* lb[2] = { &ldsbuf[0][w >> 1][w & 1][0], &ldsbuf[1][w >> 1][w & 1][0] };

    const float* m2p = m2half + h * CODES + cbase + col;

    float bv[16], bv2[16]; int bi[16];
#pragma unroll
    for (int r = 0; r < 16; ++r) { bv[r] = -1e30f; bv2[r] = -1e30f; bi[r] = 0; }

    // stage chunk 0 into dbuf 0
#pragma unroll
    for (int k = 0; k < 4; ++k)
        async_load16(gsrc + k * 1024, lb[0] + k * 1024);
    __syncthreads();

    const char* Bh = &ldsbuf[0][half][0][0];
    const char* Bl = &ldsbuf[0][half][1][0];

#pragma unroll 1
    for (int i = 0; i < 64; ++i) {
        const int d = i & 1;
        if (i + 1 < 64) {
            const char* g = gsrc + (size_t)(i + 1) * 4096;
#pragma unroll
            for (int k = 0; k < 4; ++k)
                async_load16(g + k * 1024, lb[d ^ 1] + k * 1024);
        }

        // fragments from LDS: piece p = 2t+kh, slot (p, col)
        const char* bhB = Bh + (size_t)d * (2 * 2 * 4096);
        const char* blB = Bl + (size_t)d * (2 * 2 * 4096);
        bf16x8 bh[4], blo[4];
#pragma unroll
        for (int t = 0; t < 4; ++t) {
            int off = ((2 * t + kh) * 32 + col) * 16;
            bh[t]  = *reinterpret_cast<const bf16x8*>(bhB + off);
            blo[t] = *reinterpret_cast<const bf16x8*>(blB + off);
        }
        float m2v = m2p[i * 32];
        f32x16 acc;
#pragma unroll
        for (int r = 0; r < 16; ++r) acc[r] = m2v;

        acc = __builtin_amdgcn_mfma_f32_32x32x16_bf16(ah[0], bh[0],  acc, 0, 0, 0);
        acc = __builtin_amdgcn_mfma_f32_32x32x16_bf16(ah[1], bh[1],  acc, 0, 0, 0);
        acc = __builtin_amdgcn_mfma_f32_32x32x16_bf16(ah[2], bh[2],  acc, 0, 0, 0);
        acc = __builtin_amdgcn_mfma_f32_32x32x16_bf16(ah[3], bh[3],  acc, 0, 0, 0);
        acc = __builtin_amdgcn_mfma_f32_32x32x16_bf16(al[0], bh[0],  acc, 0, 0, 0);
        acc = __builtin_amdgcn_mfma_f32_32x32x16_bf16(al[1], bh[1],  acc, 0, 0, 0);
        acc = __builtin_amdgcn_mfma_f32_32x32x16_bf16(al[2], bh[2],  acc, 0, 0, 0);
        acc = __builtin_amdgcn_mfma_f32_32x32x16_bf16(al[3], bh[3],  acc, 0, 0, 0);
        acc = __builtin_amdgcn_mfma_f32_32x32x16_bf16(ah[0], blo[0], acc, 0, 0, 0);
        acc = __builtin_amdgcn_mfma_f32_32x32x16_bf16(ah[1], blo[1], acc, 0, 0, 0);
        acc = __builtin_amdgcn_mfma_f32_32x32x16_bf16(ah[2], blo[2], acc, 0, 0, 0);
        acc = __builtin_amdgcn_mfma_f32_32x32x16_bf16(ah[3], blo[3], acc, 0, 0, 0);

        // top-2 update; this lane's single code, 16 query-rows
        int cc = cbase + i * 32 + col;
#pragma unroll
        for (int r = 0; r < 16; ++r) {
            float s = acc[r];
            bv2[r] = __builtin_amdgcn_fmed3f(bv2[r], s, bv[r]);
            bool gt = s > bv[r];
            bi[r] = gt ? cc : bi[r];
            bv[r] = fmaxf(bv[r], s);
        }
        __syncthreads();
    }

    // ---- cross-col top-2 butterfly (32 cols; masks 1..16 stay in-half) -----
#pragma unroll
    for (int r = 0; r < 16; ++r) {
#pragma unroll
        for (int m = 1; m <= 16; m <<= 1) {
            float pv1 = __shfl_xor(bv[r],  m, 64);
            float pv2 = __shfl_xor(bv2[r], m, 64);
            int   pi  = __shfl_xor(bi[r],  m, 64);
            bool take = (pv1 > bv[r]) || (pv1 == bv[r] && pi < bi[r]);
            float lo1 = take ? bv[r] : pv1;
            bv2[r] = fmaxf(lo1, fmaxf(bv2[r], pv2));
            bv[r]  = take ? pv1 : bv[r];
            bi[r]  = take ? pi  : bi[r];
        }
    }
    if (col == 0) {                     // lanes 0 and 32
#pragma unroll
        for (int r = 0; r < 16; ++r) {
            int row = (r & 3) + 8 * (r >> 2) + 4 * kh;   // D-row = query
            int ql  = qt * 32 + row;
            sbv [half][ql] = bv[r];
            sbv2[half][ql] = bv2[r];
            sbi [half][ql] = bi[r];
        }
    }
    __syncthreads();

    // ---- merge the two code halves, flag small margins ---------------------
    if (tid < 64) {
        int q = tid;
        float bvA = sbv[0][q],  bvB = sbv[1][q];
        float b2A = sbv2[0][q], b2B = sbv2[1][q];
        bool  tb  = bvB > bvA;                    // tie -> half 0 (smaller c)
        float bvm  = tb ? bvB : bvA;
        int   bim  = tb ? sbi[1][q] : sbi[0][q];
        float bv2m = fmaxf(fmaxf(b2A, b2B), fminf(bvA, bvB));
        fin[q] = bim;
        if (bvm - bv2m < TAU) {
            int slot = atomicAdd(wl_count, 1);
            if (slot < WLCAP) wl[slot] = (h << 16) | (q0 + q);
        }
    }
    __syncthreads();

    // ---- gather values[h, fin[q], :] -> out; 64 rows x 16 float4 -----------
#pragma unroll
    for (int k = 0; k < 4; ++k) {
        int f   = tid + k * 256;
        int row = f >> 4;
        int cl  = (f & 15) << 2;
        int idx = fin[row];
        float4 v = *reinterpret_cast<const float4*>(
            values + (size_t)h * CODES * DVI + (size_t)idx * DVI + cl);
        *reinterpret_cast<float4*>(
            out + (size_t)(q0 + row) * DIMX + h * DVI + cl) = v;
    }
}

// ---- pass 2: numpy-bit-exact re-argmin, 4 waves per flagged query ----------
__global__ __launch_bounds__(256) void np_recheck(const float* __restrict__ x,
                                                  const float* __restrict__ ke,
                                                  const float* __restrict__ values,
                                                  const float* __restrict__ e2np,
                                                  const int* __restrict__ wl_count,
                                                  const int* __restrict__ wl,
                                                  float* __restrict__ out) {
    __shared__ float xs[DKI];
    __shared__ float wv[4];
    __shared__ int   wi[4];
    __shared__ int   bcast;

    const int t = threadIdx.x, w = t >> 6, lane = t & 63;
    int cnt = *wl_count;
    if (cnt > WLCAP) cnt = WLCAP;

    for (int e = blockIdx.x; e < cnt; e += gridDim.x) {
        __syncthreads();
        int ent = wl[e];
        int h = ent >> 16, nq = ent & 0xffff;
        if (t < DKI) xs[t] = x[(size_t)nq * DIMX + h * DKI + t];
        __syncthreads();

        float x2 = np_sumsq64(xs);

        float best = 3.4e38f; int bestc = 0x7fffffff;
#pragma unroll 1
        for (int it = 0; it < 16; ++it) {
            int c = w * 1024 + it * 64 + lane;      // ascending per lane
            float er[DKI];
            const float4* p = reinterpret_cast<const float4*>(
                ke + ((size_t)h * CODES + c) * DKI);
#pragma unroll
            for (int i = 0; i < DKI / 4; ++i) {
                float4 v = p[i];
                er[i * 4 + 0] = v.x; er[i * 4 + 1] = v.y;
                er[i * 4 + 2] = v.z; er[i * 4 + 3] = v.w;
            }
            float dot = np_dot64(xs, er);
            float d2;
            {
#pragma clang fp contract(off)
                d2 = (x2 - 2.0f * dot) + e2np[h * CODES + c];
            }
            if (d2 < best) { best = d2; bestc = c; }
        }
        // 64-lane min butterfly with first-index tiebreak
#pragma unroll
        for (int m = 1; m <= 32; m <<= 1) {
            float pv = __shfl_xor(best, m, 64);
            int   pi = __shfl_xor(bestc, m, 64);
            if (pv < best || (pv == best && pi < bestc)) { best = pv; bestc = pi; }
        }
        if (lane == 0) { wv[w] = best; wi[w] = bestc; }
        __syncthreads();
        if (t == 0) {
            float bb = wv[0]; int bc = wi[0];
#pragma unroll
            for (int l = 1; l < 4; ++l)
                if (wv[l] < bb || (wv[l] == bb && wi[l] < bc)) { bb = wv[l]; bc = wi[l]; }
            bcast = bc;
        }
        __syncthreads();
        int c = bcast;
        if (t < DVI)
            out[(size_t)nq * DIMX + h * DVI + t] =
                values[((size_t)h * CODES + c) * DVI + t];
    }
}

extern "C" void kernel_launch(void* const* d_in, const int* in_sizes, int n_in,
                              void* d_out, int out_size, void* d_ws, size_t ws_size,
                              hipStream_t stream) {
    const float* x      = (const float*)d_in[0];
    // d_in[1] = mask (all ones; unused)
    const float* ke     = (const float*)d_in[2];
    const float* values = (const float*)d_in[3];
    // d_in[4] = key_optim (unused)
    float* out = (float*)d_out;

    char* ws = (char*)d_ws;
    float* e2np     = (float*)ws;  ws += HEADS * CODES * sizeof(float);
    float* m2half   = (float*)ws;  ws += HEADS * CODES * sizeof(float);
    int*   wl_count = (int*)ws;    ws += 16;
    int*   wl       = (int*)ws;    ws += WLCAP * sizeof(int);
    char*  EhT      = ws;          ws += (size_t)HEADS * CODES * DKI * 2;
    char*  ElT      = ws;

    prep_ke<<<dim3((HEADS * CODES + 255) / 256), dim3(256), 0, stream>>>(
        ke, (uint4*)EhT, (uint4*)ElT, e2np, m2half, wl_count);
    dkvb_mfma<<<dim3(768), dim3(256), 0, stream>>>(
        x, EhT, ElT, values, m2half, wl_count, wl, out);
    np_recheck<<<dim3(1024), dim3(256), 0, stream>>>(
        x, ke, values, e2np, wl_count, wl, out);
}